// Round 11
// baseline (563.427 us; speedup 1.0000x reference)
//
#include <hip/hip_runtime.h>
#include <hip/hip_cooperative_groups.h>
#include <math.h>

namespace cg = cooperative_groups;

#define ROWS 16384
#define DD   4096
#define EE   64
#define EPSF 1e-10f

#define BM     64                // rows per gemm block
#define KSPLIT 2                 // K halves -> 512 blocks = 2/CU
#define KRANGE (DD / KSPLIT)     // 2048 k per block
#define KT     64                // k per pipeline phase
#define NPH    (KRANGE / KT)     // 32 phases
#define WTILE  8192              // bytes per pre-split 32-k w tile (2*4*64*16)
#define BTILE  (2 * WTILE)       // bytes per 64-k phase (16384)

typedef __attribute__((ext_vector_type(8))) short short8;   // 8 bf16
typedef __attribute__((ext_vector_type(4))) float f32x4;    // MFMA C/D
typedef __attribute__((ext_vector_type(4))) unsigned u32x4; // packed bf16x8

// RNE 2-level bf16 split of 8 floats, pair-packed into 2x (4 dwords).
__device__ __forceinline__ void split2x8(const float f[8], u32x4& w0,
                                         u32x4& w1) {
#pragma unroll
  for (int i = 0; i < 4; ++i) {
    float fa = f[2 * i], fb = f[2 * i + 1];
    unsigned ua = __float_as_uint(fa), ub = __float_as_uint(fb);
    unsigned ra = ua + 0x7fffu + ((ua >> 16) & 1u);
    unsigned rb = ub + 0x7fffu + ((ub >> 16) & 1u);
    w0[i] = (rb & 0xffff0000u) | (ra >> 16);
    fa -= __uint_as_float(ra & 0xffff0000u);
    fb -= __uint_as_float(rb & 0xffff0000u);
    ua = __float_as_uint(fa); ub = __float_as_uint(fb);
    ra = ua + 0x7fffu + ((ua >> 16) & 1u);
    rb = ub + 0x7fffu + ((ub >> 16) & 1u);
    w1[i] = (rb & 0xffff0000u) | (ra >> 16);
  }
}

__device__ __forceinline__ void dma16(const void* g, void* l) {
  __builtin_amdgcn_global_load_lds(
      (const __attribute__((address_space(1))) unsigned int*)g,
      (__attribute__((address_space(3))) unsigned int*)l, 16, 0, 0);
}

// w pre-split body: one 32-k tile (kt) per 256-thr group.
__device__ __forceinline__ void wsplit_body(int kt, int t,
                                            const float* __restrict__ wr,
                                            unsigned char* __restrict__ out) {
  const int lane = t & 63, wv = t >> 6;
  float f[8];
  const float* wp = wr + (size_t)(kt * 32 + wv * 8) * EE + lane;
#pragma unroll
  for (int j = 0; j < 8; ++j) f[j] = wp[(size_t)j * EE];
  u32x4 w0, w1;
  split2x8(f, w0, w1);
  const int et = lane >> 4;
  const int lp = wv * 16 + (lane & 15);
  unsigned char* base = out + (size_t)kt * WTILE + et * 1024 + lp * 16;
  *(u32x4*)(base + 0 * 4096) = w0;
  *(u32x4*)(base + 1 * 4096) = w1;
}

// gemm stage body (R9-proven, KSPLIT=2, 4 waves): accumulates into logits.
__device__ __forceinline__ void gemm_body(
    int b, int t, unsigned char* smem, const float* __restrict__ h,
    const unsigned char* __restrict__ wsp, float* __restrict__ logits) {
  const int lane = t & 63;
  const int wv = t >> 6;    // 0..3 = m-tile (16 rows each)
  const int row0 = (b >> 1) * BM;
  const int ks = b & 1;

  f32x4 acc[4] = {};

  const float* ap = h + (size_t)(row0 + wv * 16 + (lane & 15)) * DD +
                    ks * KRANGE + (lane >> 4) * 8;
  const unsigned char* wbase = wsp + (size_t)ks * NPH * BTILE;
  const int dmaoff = t * 16;

  float4 c0, c1, c2, c3, n0, n1, n2, n3;

#pragma unroll
  for (int i = 0; i < 4; ++i)
    dma16(wbase + i * 4096 + dmaoff, smem + i * 4096 + dmaoff);
  c0 = *(const float4*)(ap);
  c1 = *(const float4*)(ap + 4);
  c2 = *(const float4*)(ap + 32);
  c3 = *(const float4*)(ap + 36);

  for (int kt = 0; kt < NPH; ++kt) {
    const int buf = kt & 1;
    asm volatile("s_waitcnt vmcnt(0)" ::: "memory");
    __syncthreads();

    if (kt + 1 < NPH) {
      const unsigned char* ws = wbase + (size_t)(kt + 1) * BTILE;
      unsigned char* nb = smem + (buf ^ 1) * BTILE;
#pragma unroll
      for (int i = 0; i < 4; ++i)
        dma16(ws + i * 4096 + dmaoff, nb + i * 4096 + dmaoff);
      const float* p = ap + (size_t)(kt + 1) * KT;
      n0 = *(const float4*)(p);
      n1 = *(const float4*)(p + 4);
      n2 = *(const float4*)(p + 32);
      n3 = *(const float4*)(p + 36);
    }

    const unsigned char* lb = smem + buf * BTILE;
#pragma unroll
    for (int sub = 0; sub < 2; ++sub) {
      const unsigned char* sb = lb + sub * WTILE;
      short8 bf[2][4];
#pragma unroll
      for (int p = 0; p < 2; ++p)
#pragma unroll
        for (int e = 0; e < 4; ++e)
          bf[p][e] = *(const short8*)&sb[p * 4096 + e * 1024 + lane * 16];

      const float4 a0 = sub ? c2 : c0;
      const float4 a1 = sub ? c3 : c1;
      const float af[8] = {a0.x, a0.y, a0.z, a0.w, a1.x, a1.y, a1.z, a1.w};
      u32x4 q0, q1;
      split2x8(af, q0, q1);
      const short8 ah0 = __builtin_bit_cast(short8, q0);
      const short8 ah1 = __builtin_bit_cast(short8, q1);
#pragma unroll
      for (int e = 0; e < 4; ++e) {
        f32x4 c = acc[e];
        c = __builtin_amdgcn_mfma_f32_16x16x32_bf16(ah0, bf[0][e], c, 0, 0, 0);
        c = __builtin_amdgcn_mfma_f32_16x16x32_bf16(ah0, bf[1][e], c, 0, 0, 0);
        c = __builtin_amdgcn_mfma_f32_16x16x32_bf16(ah1, bf[0][e], c, 0, 0, 0);
        acc[e] = c;
      }
    }

    if (kt + 1 < NPH) { c0 = n0; c1 = n1; c2 = n2; c3 = n3; }
  }

  const int rbase = row0 + wv * 16 + (lane >> 4) * 4;
  const int col = lane & 15;
#pragma unroll
  for (int e = 0; e < 4; ++e)
#pragma unroll
    for (int r = 0; r < 4; ++r)
      atomicAdd(&logits[(size_t)(rbase + r) * EE + e * 16 + col],
                acc[e][r]);
}

// ---------------------------------------------------------------------------
// ONE cooperative kernel: wsplit+zero -> gemm -> softload -> penalty+top2.
// 512 blocks x 256 thr (2/CU; 32KB LDS, ~70 VGPR -> residency safe).
// Stage 2 stashes this block's 32 logits rows in LDS; stage 3 serves the
// penalty/top-2 from LDS (saves a full 4 MB global re-read + 3 launches).
// ---------------------------------------------------------------------------
__global__ __launch_bounds__(256, 2) void k_fused(
    const float* __restrict__ h, const float* __restrict__ wr,
    unsigned char* __restrict__ wsp, float* __restrict__ logits,
    float* __restrict__ g_load, float* __restrict__ idx_out) {
  __shared__ alignas(16) unsigned char smem[2 * BTILE];  // 32 KB
  cg::grid_group grid = cg::this_grid();
  const int b = blockIdx.x;
  const int t = threadIdx.x;
  const int lane = t & 63;
  const int wv = t >> 6;

  // ---- stage 0: w pre-split (blocks 0-127), zero logits (128-255), g_load
  if (b < 128) {
    if (b == 0 && t < 64) g_load[t] = 0.f;
    wsplit_body(b, t, wr, wsp);
  } else if (b < 256) {
    float4 z = {0.f, 0.f, 0.f, 0.f};
    float4* lp4 = (float4*)logits + (size_t)(b - 128) * 2048 + t;
#pragma unroll
    for (int i = 0; i < 8; ++i) lp4[i * 256] = z;
  }
  grid.sync();

  // ---- stage 1: router GEMM (R9-proven body) ----
  gemm_body(b, t, smem, h, wsp, logits);
  grid.sync();

  // ---- stage 2: softmax + expert load; stash rows in LDS ----
  float* sl2 = (float*)smem;               // [32][64] this block's logits rows
  float* red = (float*)(smem + 8192);      // [4][64]
  const int rows0 = b * 32;
  float accp = 0.f;
#pragma unroll
  for (int i = 0; i < 8; ++i) {
    const int row = rows0 + wv * 8 + i;
    const float x = logits[(size_t)row * EE + lane];
    sl2[(wv * 8 + i) * 64 + lane] = x;
    float m = x;
#pragma unroll
    for (int off = 32; off > 0; off >>= 1) m = fmaxf(m, __shfl_xor(m, off, 64));
    const float p = __expf(x - m);
    float s = p;
#pragma unroll
    for (int off = 32; off > 0; off >>= 1) s += __shfl_xor(s, off, 64);
    accp += p / s;
  }
  red[wv * 64 + lane] = accp;
  __syncthreads();
  if (wv == 0) {
    float s = red[0 * 64 + lane] + red[1 * 64 + lane] + red[2 * 64 + lane] +
              red[3 * 64 + lane];
    atomicAdd(&g_load[lane], s);
  }
  grid.sync();

  // ---- stage 3: penalty + adjusted logits + top-2 (rows from LDS) ----
  float v0 = g_load[lane];
  float s0 = v0;
#pragma unroll
  for (int off = 32; off > 0; off >>= 1) s0 += __shfl_xor(s0, off, 64);
  const float lp = logf(v0 / (s0 * (1.f / 64.f) + EPSF) + EPSF);

#pragma unroll
  for (int i = 0; i < 8; ++i) {
    const int row = rows0 + wv * 8 + i;
    const float a = sl2[(wv * 8 + i) * 64 + lane] - lp;
    logits[(size_t)row * EE + lane] = a;

    float v = a;
    int idx = lane;
#pragma unroll
    for (int off = 32; off > 0; off >>= 1) {
      float ov = __shfl_xor(v, off, 64);
      int oi = __shfl_xor(idx, off, 64);
      if (ov > v || (ov == v && oi < idx)) { v = ov; idx = oi; }
    }
    const int i1 = idx;
    float a2 = (lane == i1) ? -INFINITY : a;
    v = a2;
    idx = lane;
#pragma unroll
    for (int off = 32; off > 0; off >>= 1) {
      float ov = __shfl_xor(v, off, 64);
      int oi = __shfl_xor(idx, off, 64);
      if (ov > v || (ov == v && oi < idx)) { v = ov; idx = oi; }
    }
    const int i2 = idx;
    if (lane == 0) {
      idx_out[(size_t)row * 2 + 0] = (float)i1;
      idx_out[(size_t)row * 2 + 1] = (float)i2;
    }
  }
}

// ======================= fallback path (R9-proven) =========================
__global__ __launch_bounds__(256) void k_wsplit(const float* __restrict__ wr,
                                                unsigned char* __restrict__ out,
                                                float* __restrict__ logits,
                                                float* __restrict__ g_load) {
  const int kt = blockIdx.x;
  const int t = threadIdx.x;
  if (blockIdx.x == 0 && t < 64) g_load[t] = 0.f;
  {
    float4 z = {0.f, 0.f, 0.f, 0.f};
    float4* lp4 = (float4*)logits + (size_t)blockIdx.x * 2048 + t;
#pragma unroll
    for (int i = 0; i < 8; ++i) lp4[i * 256] = z;
  }
  wsplit_body(kt, t, wr, out);
}

__global__ __launch_bounds__(256) void k_gemm(
    const float* __restrict__ h, const unsigned char* __restrict__ wsp,
    float* __restrict__ logits) {
  __shared__ alignas(16) unsigned char smem[2 * BTILE];
  gemm_body(blockIdx.x, threadIdx.x, smem, h, wsp, logits);
}

__global__ __launch_bounds__(256) void k_softload(
    const float* __restrict__ logits, float* __restrict__ g_load) {
  __shared__ float red[4][64];
  const int lane = threadIdx.x & 63;
  const int wv = threadIdx.x >> 6;
  float accp = 0.f;
#pragma unroll 4
  for (int i = 0; i < 16; ++i) {
    int row = blockIdx.x * 64 + wv * 16 + i;
    float x = logits[(size_t)row * EE + lane];
    float m = x;
#pragma unroll
    for (int off = 32; off > 0; off >>= 1) m = fmaxf(m, __shfl_xor(m, off, 64));
    float p = __expf(x - m);
    float s = p;
#pragma unroll
    for (int off = 32; off > 0; off >>= 1) s += __shfl_xor(s, off, 64);
    accp += p / s;
  }
  red[wv][lane] = accp;
  __syncthreads();
  if (wv == 0) {
    float s = red[0][lane] + red[1][lane] + red[2][lane] + red[3][lane];
    atomicAdd(&g_load[lane], s);
  }
}

__global__ __launch_bounds__(256) void k_top2(float* __restrict__ logits,
                                              const float* __restrict__ g_load,
                                              float* __restrict__ idx_out) {
  int t = threadIdx.x;
  int lane = t & 63;
  int wv = t >> 6;
  int row = blockIdx.x * 4 + wv;

  float v0 = g_load[lane];
  float s0 = v0;
#pragma unroll
  for (int off = 32; off > 0; off >>= 1) s0 += __shfl_xor(s0, off, 64);
  float lp = logf(v0 / (s0 * (1.f / 64.f) + EPSF) + EPSF);

  size_t base = (size_t)row * EE;
  float a = logits[base + lane] - lp;
  logits[base + lane] = a;

  float v = a;
  int idx = lane;
#pragma unroll
  for (int off = 32; off > 0; off >>= 1) {
    float ov = __shfl_xor(v, off, 64);
    int oi = __shfl_xor(idx, off, 64);
    if (ov > v || (ov == v && oi < idx)) { v = ov; idx = oi; }
  }
  int i1 = idx;

  float a2 = (lane == i1) ? -INFINITY : a;
  v = a2;
  idx = lane;
#pragma unroll
  for (int off = 32; off > 0; off >>= 1) {
    float ov = __shfl_xor(v, off, 64);
    int oi = __shfl_xor(idx, off, 64);
    if (ov > v || (ov == v && oi < idx)) { v = ov; idx = oi; }
  }
  int i2 = idx;

  if (lane == 0) {
    idx_out[(size_t)row * 2 + 0] = (float)i1;
    idx_out[(size_t)row * 2 + 1] = (float)i2;
  }
}

// ---------------------------------------------------------------------------
extern "C" void kernel_launch(void* const* d_in, const int* in_sizes, int n_in,
                              void* d_out, int out_size, void* d_ws,
                              size_t ws_size, hipStream_t stream) {
  const float* h = (const float*)d_in[0];   // [4,4096,4096]
  const float* wr = (const float*)d_in[1];  // [4096,64]
  float* out = (float*)d_out;
  float* logits = out;                          // ROWS*EE (raw, then adjusted)
  float* idx_out = out + (size_t)ROWS * EE;     // ROWS*2
  float* g_load = (float*)d_ws;                 // 64 floats
  unsigned char* wsp = (unsigned char*)d_ws + 512;  // 1 MiB pre-split w

  void* args[6] = {(void*)&h,      (void*)&wr,     (void*)&wsp,
                   (void*)&logits, (void*)&g_load, (void*)&idx_out};
  hipError_t err = hipLaunchCooperativeKernel(
      (const void*)k_fused, dim3((ROWS / BM) * KSPLIT), dim3(256), args, 0,
      stream);
  if (err != hipSuccess) {
    // R9-proven 4-launch fallback (identical numerics)
    k_wsplit<<<DD / 32, 256, 0, stream>>>(wr, wsp, logits, g_load);
    k_gemm<<<(ROWS / BM) * KSPLIT, 256, 0, stream>>>(h, wsp, logits);
    k_softload<<<ROWS / 64, 256, 0, stream>>>(logits, g_load);
    k_top2<<<ROWS / 4, 256, 0, stream>>>(logits, g_load, idx_out);
  }
}

// Round 12
// 515.858 us; speedup vs baseline: 1.0922x; 1.0922x over previous
//
#include <hip/hip_runtime.h>
#include <math.h>

#define ROWS 16384
#define DD   4096
#define EE   64
#define EPSF 1e-10f

#define BM     64                // rows per gemm block
#define KSPLIT 2                 // K halves -> 512 blocks = 2/CU
#define KRANGE (DD / KSPLIT)     // 2048 k per block
#define KT     64                // k per pipeline phase
#define NPH    (KRANGE / KT)     // 32 phases
#define WTILE  8192              // bytes per pre-split 32-k w tile (2*4*64*16)
#define BTILE  (2 * WTILE)       // bytes per 64-k phase (16384)

typedef __attribute__((ext_vector_type(8))) short short8;   // 8 bf16
typedef __attribute__((ext_vector_type(4))) float f32x4;    // MFMA C/D
typedef __attribute__((ext_vector_type(4))) unsigned u32x4; // packed bf16x8

// RNE 2-level bf16 split of 8 floats, pair-packed into 2x (4 dwords).
__device__ __forceinline__ void split2x8(const float f[8], u32x4& w0,
                                         u32x4& w1) {
#pragma unroll
  for (int i = 0; i < 4; ++i) {
    float fa = f[2 * i], fb = f[2 * i + 1];
    unsigned ua = __float_as_uint(fa), ub = __float_as_uint(fb);
    unsigned ra = ua + 0x7fffu + ((ua >> 16) & 1u);
    unsigned rb = ub + 0x7fffu + ((ub >> 16) & 1u);
    w0[i] = (rb & 0xffff0000u) | (ra >> 16);
    fa -= __uint_as_float(ra & 0xffff0000u);
    fb -= __uint_as_float(rb & 0xffff0000u);
    ua = __float_as_uint(fa); ub = __float_as_uint(fb);
    ra = ua + 0x7fffu + ((ua >> 16) & 1u);
    rb = ub + 0x7fffu + ((ub >> 16) & 1u);
    w1[i] = (rb & 0xffff0000u) | (ra >> 16);
  }
}

__device__ __forceinline__ void dma16(const void* g, void* l) {
  __builtin_amdgcn_global_load_lds(
      (const __attribute__((address_space(1))) unsigned int*)g,
      (__attribute__((address_space(3))) unsigned int*)l, 16, 0, 0);
}

// ---------------------------------------------------------------------------
// One-time w pre-split (2-part) into MFMA-B-fragment-ready layout:
//   wsp[kt32][part p(2)][et(4)][lp(64)][8 bf16]; lp = k_octet*16 + (e&15).
// Also zeroes the 4 MB partial buffer, g_load, and the 256 pair-counters
// (all re-poisoned by the harness each iteration; stream-ordered here).
// ---------------------------------------------------------------------------
__global__ __launch_bounds__(256) void k_wsplit(const float* __restrict__ wr,
                                                unsigned char* __restrict__ out,
                                                float* __restrict__ partial,
                                                float* __restrict__ g_load,
                                                int* __restrict__ counters) {
  const int kt = blockIdx.x;  // global 32-k tile 0..127
  const int t = threadIdx.x;
  const int lane = t & 63, wv = t >> 6;
  if (blockIdx.x == 0) {
    if (t < 64) g_load[t] = 0.f;
    counters[t] = 0;  // 256 counters, one per row-block pair
  }
  // zero partial: 128 blocks x 256 thr x 8 float4 stores = 4 MiB coalesced
  {
    float4 z = {0.f, 0.f, 0.f, 0.f};
    float4* pp = (float4*)partial + (size_t)blockIdx.x * 2048 + t;
#pragma unroll
    for (int i = 0; i < 8; ++i) pp[i * 256] = z;
  }
  float f[8];
  const float* wp = wr + (size_t)(kt * 32 + wv * 8) * EE + lane;
#pragma unroll
  for (int j = 0; j < 8; ++j) f[j] = wp[(size_t)j * EE];
  u32x4 w0, w1;
  split2x8(f, w0, w1);
  const int et = lane >> 4;
  const int lp = wv * 16 + (lane & 15);
  unsigned char* base = out + (size_t)kt * WTILE + et * 1024 + lp * 16;
  *(u32x4*)(base + 0 * 4096) = w0;
  *(u32x4*)(base + 1 * 4096) = w1;
}

// ---------------------------------------------------------------------------
// Router GEMM + last-arriver fused epilogue.
// 512 blocks x 256 thr (4 waves) = 2 blocks/CU (R4/R9-proven best service
// config). Block = 64 rows x K-half 2048 (KSPLIT=2). Wave = m-tile (16 rows),
// both 32-k subtiles per phase, all 4 e-tiles; 2-part/3-term split product.
// After the K-loop both partner blocks atomically accumulate partials; the
// SECOND arriver at the per-row-block counter (threadfence release/acquire,
// no spinning -> deadlock-free regardless of scheduling) reads the completed
// 64 full-K rows coalesced and runs the fused softmax + expert-load + raw
// logit store (R7-proven math). Eliminates the separate k_softload pass.
// ---------------------------------------------------------------------------
__global__ __launch_bounds__(256) void k_gemm(
    const float* __restrict__ h, const unsigned char* __restrict__ wsp,
    float* __restrict__ partial, float* __restrict__ logits,
    float* __restrict__ g_load, int* __restrict__ counters) {
  __shared__ alignas(16) unsigned char smem[2 * BTILE];  // 32 KB B staging
  __shared__ float red[4][64];
  __shared__ int lastFlag;

  const int t = threadIdx.x;
  const int lane = t & 63;
  const int wv = t >> 6;    // 0..3 = m-tile (16 rows each)
  const int rb = blockIdx.x >> 1;   // row-block 0..255
  const int ks = blockIdx.x & 1;    // K-half
  const int row0 = rb * BM;

  f32x4 acc[4] = {};

  const float* ap = h + (size_t)(row0 + wv * 16 + (lane & 15)) * DD +
                    ks * KRANGE + (lane >> 4) * 8;
  const unsigned char* wbase = wsp + (size_t)ks * NPH * BTILE;
  const int dmaoff = t * 16;

  float4 c0, c1, c2, c3, n0, n1, n2, n3;

#pragma unroll
  for (int i = 0; i < 4; ++i)
    dma16(wbase + i * 4096 + dmaoff, smem + i * 4096 + dmaoff);
  c0 = *(const float4*)(ap);
  c1 = *(const float4*)(ap + 4);
  c2 = *(const float4*)(ap + 32);
  c3 = *(const float4*)(ap + 36);

  for (int kt = 0; kt < NPH; ++kt) {
    const int buf = kt & 1;
    asm volatile("s_waitcnt vmcnt(0)" ::: "memory");
    __syncthreads();

    if (kt + 1 < NPH) {
      const unsigned char* ws = wbase + (size_t)(kt + 1) * BTILE;
      unsigned char* nb = smem + (buf ^ 1) * BTILE;
#pragma unroll
      for (int i = 0; i < 4; ++i)
        dma16(ws + i * 4096 + dmaoff, nb + i * 4096 + dmaoff);
      const float* p = ap + (size_t)(kt + 1) * KT;
      n0 = *(const float4*)(p);
      n1 = *(const float4*)(p + 4);
      n2 = *(const float4*)(p + 32);
      n3 = *(const float4*)(p + 36);
    }

    const unsigned char* lb = smem + buf * BTILE;
#pragma unroll
    for (int sub = 0; sub < 2; ++sub) {
      const unsigned char* sb = lb + sub * WTILE;
      short8 bf[2][4];
#pragma unroll
      for (int p = 0; p < 2; ++p)
#pragma unroll
        for (int e = 0; e < 4; ++e)
          bf[p][e] = *(const short8*)&sb[p * 4096 + e * 1024 + lane * 16];

      const float4 a0 = sub ? c2 : c0;
      const float4 a1 = sub ? c3 : c1;
      const float af[8] = {a0.x, a0.y, a0.z, a0.w, a1.x, a1.y, a1.z, a1.w};
      u32x4 q0, q1;
      split2x8(af, q0, q1);
      const short8 ah0 = __builtin_bit_cast(short8, q0);
      const short8 ah1 = __builtin_bit_cast(short8, q1);
#pragma unroll
      for (int e = 0; e < 4; ++e) {
        f32x4 c = acc[e];
        c = __builtin_amdgcn_mfma_f32_16x16x32_bf16(ah0, bf[0][e], c, 0, 0, 0);
        c = __builtin_amdgcn_mfma_f32_16x16x32_bf16(ah0, bf[1][e], c, 0, 0, 0);
        c = __builtin_amdgcn_mfma_f32_16x16x32_bf16(ah1, bf[0][e], c, 0, 0, 0);
        acc[e] = c;
      }
    }

    if (kt + 1 < NPH) { c0 = n0; c1 = n1; c2 = n2; c3 = n3; }
  }

  // ---- accumulate K-half partials (C layout: col=lane&15, row=quad*4+r) ----
  const int rbase = row0 + wv * 16 + (lane >> 4) * 4;
  const int col = lane & 15;
#pragma unroll
  for (int e = 0; e < 4; ++e)
#pragma unroll
    for (int r = 0; r < 4; ++r)
      atomicAdd(&partial[(size_t)(rbase + r) * EE + e * 16 + col],
                acc[e][r]);

  // ---- last-arriver election (canonical threadfence + counter idiom) ----
  __threadfence();
  if (t == 0) lastFlag = (atomicAdd(&counters[rb], 1) == 1);
  __syncthreads();
  if (!lastFlag) return;
  __threadfence();  // acquire partner's partials

  // ---- fused epilogue: softmax + expert load + raw logit store ----
  float accp = 0.f;
#pragma unroll
  for (int i = 0; i < 16; ++i) {
    const int row = row0 + wv * 16 + i;
    const float x = partial[(size_t)row * EE + lane];   // full-K sum
    float m = x;
#pragma unroll
    for (int off = 32; off > 0; off >>= 1) m = fmaxf(m, __shfl_xor(m, off, 64));
    const float p = __expf(x - m);
    float s = p;
#pragma unroll
    for (int off = 32; off > 0; off >>= 1) s += __shfl_xor(s, off, 64);
    accp += p / s;
    logits[(size_t)row * EE + lane] = x;                // raw, coalesced
  }
  red[wv][lane] = accp;
  __syncthreads();
  if (wv == 0) {
    float s = red[0][lane] + red[1][lane] + red[2][lane] + red[3][lane];
    atomicAdd(&g_load[lane], s);
  }
}

// ---------------------------------------------------------------------------
// penalty (recomputed per wave: 64-wide reduce + logf, trivially cheap)
// + adjusted logits + top-2. One row per wave.
// ---------------------------------------------------------------------------
__global__ __launch_bounds__(256) void k_top2(float* __restrict__ logits,
                                              const float* __restrict__ g_load,
                                              float* __restrict__ idx_out) {
  int t = threadIdx.x;
  int lane = t & 63;
  int wv = t >> 6;
  int row = blockIdx.x * 4 + wv;

  float v0 = g_load[lane];
  float s0 = v0;
#pragma unroll
  for (int off = 32; off > 0; off >>= 1) s0 += __shfl_xor(s0, off, 64);
  float lp = logf(v0 / (s0 * (1.f / 64.f) + EPSF) + EPSF);

  size_t base = (size_t)row * EE;
  float a = logits[base + lane] - lp;
  logits[base + lane] = a;

  float v = a;
  int idx = lane;
#pragma unroll
  for (int off = 32; off > 0; off >>= 1) {
    float ov = __shfl_xor(v, off, 64);
    int oi = __shfl_xor(idx, off, 64);
    if (ov > v || (ov == v && oi < idx)) { v = ov; idx = oi; }
  }
  int i1 = idx;

  float a2 = (lane == i1) ? -INFINITY : a;
  v = a2;
  idx = lane;
#pragma unroll
  for (int off = 32; off > 0; off >>= 1) {
    float ov = __shfl_xor(v, off, 64);
    int oi = __shfl_xor(idx, off, 64);
    if (ov > v || (ov == v && oi < idx)) { v = ov; idx = oi; }
  }
  int i2 = idx;

  if (lane == 0) {
    idx_out[(size_t)row * 2 + 0] = (float)i1;
    idx_out[(size_t)row * 2 + 1] = (float)i2;
  }
}

// ---------------------------------------------------------------------------
extern "C" void kernel_launch(void* const* d_in, const int* in_sizes, int n_in,
                              void* d_out, int out_size, void* d_ws,
                              size_t ws_size, hipStream_t stream) {
  const float* h = (const float*)d_in[0];   // [4,4096,4096]
  const float* wr = (const float*)d_in[1];  // [4096,64]
  float* out = (float*)d_out;
  float* logits = out;                          // ROWS*EE (raw, then adjusted)
  float* idx_out = out + (size_t)ROWS * EE;     // ROWS*2

  unsigned char* ws = (unsigned char*)d_ws;
  float* g_load = (float*)ws;                         // 64 f   @ 0
  int* counters = (int*)(ws + 256);                   // 256 i  @ 256
  unsigned char* wsp = ws + 4096;                     // 1 MiB  @ 4096
  float* partial = (float*)(ws + (2u << 20));         // 4 MiB  @ 2 MiB

  // g_load/counters/partial zeroed inside k_wsplit (stream-ordered).
  k_wsplit<<<DD / 32, 256, 0, stream>>>(wr, wsp, partial, g_load, counters);
  k_gemm<<<(ROWS / BM) * KSPLIT, 256, 0, stream>>>(h, wsp, partial, logits,
                                                   g_load, counters);
  k_top2<<<ROWS / 4, 256, 0, stream>>>(logits, g_load, idx_out);
}

// Round 13
// 397.917 us; speedup vs baseline: 1.4159x; 1.2964x over previous
//
#include <hip/hip_runtime.h>
#include <math.h>

#define ROWS 16384
#define DD   4096
#define EE   64
#define EPSF 1e-10f

#define BM    32                 // rows per gemm block -> 512 blocks = 2/CU
#define KT    64                 // k per pipeline phase (2 x 32-k subtiles)
#define NKT   (DD / KT)          // 64 phases, full K per block (KSPLIT=1)
#define WTILE 8192               // bytes per pre-split 32-k w tile (2*4*64*16)
#define BTILE (2 * WTILE)        // bytes per 64-k phase (16384)

typedef __attribute__((ext_vector_type(8))) short short8;   // 8 bf16
typedef __attribute__((ext_vector_type(4))) float f32x4;    // MFMA C/D
typedef __attribute__((ext_vector_type(4))) unsigned u32x4; // packed bf16x8

// RNE 2-level bf16 split of 8 floats, pair-packed into 2x (4 dwords).
// a ~= a0 + a1 with |a - a0 - a1| <= 2^-18 |a|.
__device__ __forceinline__ void split2x8(const float f[8], u32x4& w0,
                                         u32x4& w1) {
#pragma unroll
  for (int i = 0; i < 4; ++i) {
    float fa = f[2 * i], fb = f[2 * i + 1];
    unsigned ua = __float_as_uint(fa), ub = __float_as_uint(fb);
    unsigned ra = ua + 0x7fffu + ((ua >> 16) & 1u);
    unsigned rb = ub + 0x7fffu + ((ub >> 16) & 1u);
    w0[i] = (rb & 0xffff0000u) | (ra >> 16);
    fa -= __uint_as_float(ra & 0xffff0000u);
    fb -= __uint_as_float(rb & 0xffff0000u);
    ua = __float_as_uint(fa); ub = __float_as_uint(fb);
    ra = ua + 0x7fffu + ((ua >> 16) & 1u);
    rb = ub + 0x7fffu + ((ub >> 16) & 1u);
    w1[i] = (rb & 0xffff0000u) | (ra >> 16);
  }
}

__device__ __forceinline__ void dma16(const void* g, void* l) {
  __builtin_amdgcn_global_load_lds(
      (const __attribute__((address_space(1))) unsigned int*)g,
      (__attribute__((address_space(3))) unsigned int*)l, 16, 0, 0);
}

// ---------------------------------------------------------------------------
// One-time w pre-split (2-part) into MFMA-B-fragment-ready layout:
//   wsp[kt32][part p(2)][et(4)][lp(64)][8 bf16]; lp = k_octet*16 + (e&15).
// Block 0 also zeroes g_load (stream-ordered before k_gemm's atomics).
// ---------------------------------------------------------------------------
__global__ __launch_bounds__(256) void k_wsplit(const float* __restrict__ wr,
                                                unsigned char* __restrict__ out,
                                                float* __restrict__ g_load) {
  const int kt = blockIdx.x;  // global 32-k tile 0..127
  const int t = threadIdx.x;
  const int lane = t & 63, wv = t >> 6;
  if (blockIdx.x == 0 && t < 64) g_load[t] = 0.f;
  float f[8];
  const float* wp = wr + (size_t)(kt * 32 + wv * 8) * EE + lane;
#pragma unroll
  for (int j = 0; j < 8; ++j) f[j] = wp[(size_t)j * EE];
  u32x4 w0, w1;
  split2x8(f, w0, w1);
  const int et = lane >> 4;
  const int lp = wv * 16 + (lane & 15);
  unsigned char* base = out + (size_t)kt * WTILE + et * 1024 + lp * 16;
  *(u32x4*)(base + 0 * 4096) = w0;
  *(u32x4*)(base + 1 * 4096) = w1;
}

// ---------------------------------------------------------------------------
// Router GEMM + fused softmax/expert-load.
// 512 blocks x 256 thr (4 waves) = 2 blocks/CU (R4/R9-proven service config)
// with FULL K per block (KSPLIT=1) -> fused epilogue, no cross-block handoff.
// Block = 32 rows x 64 experts x K=4096. Wave wv: m-tile mt=wv>>1 (16 rows),
// k-subtile sub=wv&1 (32 of 64 k/phase), all 4 e-tiles; split2x8 runs once
// per A fragment. 3-term split product (a0b0+a0b1+a1b0), logit err ~1e-5.
// Proven sync skeleton: one vmcnt(0)+__syncthreads per phase, prefetch
// issued immediately after the barrier. Epilogue: pair-wave k-sum in LDS
// (R6-proven) -> per-row softmax + expert-load + raw logit store (R7-proven).
// ---------------------------------------------------------------------------
__global__ __launch_bounds__(256) void k_gemm(
    const float* __restrict__ h, const unsigned char* __restrict__ wsp,
    float* __restrict__ logits, float* __restrict__ g_load) {
  __shared__ alignas(16) unsigned char smem[2 * BTILE];  // 32 KB

  const int t = threadIdx.x;
  const int lane = t & 63;
  const int wv = t >> 6;    // 0..3
  const int mt = wv >> 1;   // m-tile 0..1 (16 rows each)
  const int sub = wv & 1;   // k-subtile 0..1 (32 k each)
  const int row0 = blockIdx.x * BM;

  f32x4 acc[4] = {};        // 4 e-tiles, partial over this wave's k-subtiles

  // A: row = row0 + mt*16 + (lane&15), k = kt*64 + sub*32 + (lane>>4)*8 + j
  const float* ap = h + (size_t)(row0 + mt * 16 + (lane & 15)) * DD +
                    sub * 32 + (lane >> 4) * 8;
  const int dmaoff = t * 16;  // + i*4096 ; dest = wave-uniform base + lane*16

  float4 c0, c1, n0, n1;

  // prologue: phase 0 (B 16 KB via 4 DMA chunks, A 8 floats to regs)
#pragma unroll
  for (int i = 0; i < 4; ++i)
    dma16(wsp + i * 4096 + dmaoff, smem + i * 4096 + dmaoff);
  c0 = *(const float4*)(ap);
  c1 = *(const float4*)(ap + 4);

  for (int kt = 0; kt < NKT; ++kt) {
    const int buf = kt & 1;
    asm volatile("s_waitcnt vmcnt(0)" ::: "memory");
    __syncthreads();

    // issue next-phase prefetch NOW; full compute phase to land
    if (kt + 1 < NKT) {
      const unsigned char* ws = wsp + (size_t)(kt + 1) * BTILE;
      unsigned char* nb = smem + (buf ^ 1) * BTILE;
#pragma unroll
      for (int i = 0; i < 4; ++i)
        dma16(ws + i * 4096 + dmaoff, nb + i * 4096 + dmaoff);
      const float* p = ap + (size_t)(kt + 1) * KT;
      n0 = *(const float4*)(p);
      n1 = *(const float4*)(p + 4);
    }

    // B fragments for this wave's k-subtile: 2 parts x 4 e-tiles
    const unsigned char* lb = smem + buf * BTILE + sub * WTILE;
    short8 bf[2][4];
#pragma unroll
    for (int p = 0; p < 2; ++p)
#pragma unroll
      for (int e = 0; e < 4; ++e)
        bf[p][e] = *(const short8*)&lb[p * 4096 + e * 1024 + lane * 16];

    // split this wave's A fragment ONCE (2-part)
    const float af[8] = {c0.x, c0.y, c0.z, c0.w, c1.x, c1.y, c1.z, c1.w};
    u32x4 q0, q1;
    split2x8(af, q0, q1);
    const short8 ah0 = __builtin_bit_cast(short8, q0);
    const short8 ah1 = __builtin_bit_cast(short8, q1);
#pragma unroll
    for (int e = 0; e < 4; ++e) {
      f32x4 c = acc[e];
      c = __builtin_amdgcn_mfma_f32_16x16x32_bf16(ah0, bf[0][e], c, 0, 0, 0);
      c = __builtin_amdgcn_mfma_f32_16x16x32_bf16(ah0, bf[1][e], c, 0, 0, 0);
      c = __builtin_amdgcn_mfma_f32_16x16x32_bf16(ah1, bf[0][e], c, 0, 0, 0);
      acc[e] = c;
    }

    if (kt + 1 < NKT) { c0 = n0; c1 = n1; }
  }

  // ---- fused epilogue: pair-wave k-sum -> softmax -> load accumulation ----
  asm volatile("s_waitcnt vmcnt(0)" ::: "memory");
  __syncthreads();                       // all waves done with smem B buffers
  float* sl = (float*)smem;              // [32][68] fp32, padded stride
  {
    const int rb = mt * 16 + (lane >> 4) * 4;     // C: row=quad*4+r
    const int cb = lane & 15;                     //    col=lane&15
    if (sub == 0) {
#pragma unroll
      for (int e = 0; e < 4; ++e)
#pragma unroll
        for (int r = 0; r < 4; ++r)
          sl[(rb + r) * 68 + e * 16 + cb] = acc[e][r];
    }
    __syncthreads();
    if (sub == 1) {
#pragma unroll
      for (int e = 0; e < 4; ++e)
#pragma unroll
        for (int r = 0; r < 4; ++r)
          sl[(rb + r) * 68 + e * 16 + cb] += acc[e][r];
    }
    __syncthreads();
  }

  float accp = 0.f;
#pragma unroll
  for (int i = 0; i < 8; ++i) {
    const int row = wv * 8 + i;
    const float x = sl[row * 68 + lane];
    float m = x;
#pragma unroll
    for (int off = 32; off > 0; off >>= 1) m = fmaxf(m, __shfl_xor(m, off, 64));
    const float p = __expf(x - m);
    float s = p;
#pragma unroll
    for (int off = 32; off > 0; off >>= 1) s += __shfl_xor(s, off, 64);
    accp += p / s;
    logits[(size_t)(row0 + row) * EE + lane] = x;   // raw logits, coalesced
  }
  float* red = sl + 32 * 68;             // disjoint LDS region
  red[wv * 64 + lane] = accp;
  __syncthreads();
  if (wv == 0) {
    float s = red[0 * 64 + lane] + red[1 * 64 + lane] + red[2 * 64 + lane] +
              red[3 * 64 + lane];
    atomicAdd(&g_load[lane], s);
  }
}

// ---------------------------------------------------------------------------
// penalty (recomputed per wave: 64-wide reduce + logf, trivially cheap)
// + adjusted logits + top-2. One row per wave.
// ---------------------------------------------------------------------------
__global__ __launch_bounds__(256) void k_top2(float* __restrict__ logits,
                                              const float* __restrict__ g_load,
                                              float* __restrict__ idx_out) {
  int t = threadIdx.x;
  int lane = t & 63;
  int wv = t >> 6;
  int row = blockIdx.x * 4 + wv;

  float v0 = g_load[lane];
  float s0 = v0;
#pragma unroll
  for (int off = 32; off > 0; off >>= 1) s0 += __shfl_xor(s0, off, 64);
  float lp = logf(v0 / (s0 * (1.f / 64.f) + EPSF) + EPSF);

  size_t base = (size_t)row * EE;
  float a = logits[base + lane] - lp;
  logits[base + lane] = a;

  float v = a;
  int idx = lane;
#pragma unroll
  for (int off = 32; off > 0; off >>= 1) {
    float ov = __shfl_xor(v, off, 64);
    int oi = __shfl_xor(idx, off, 64);
    if (ov > v || (ov == v && oi < idx)) { v = ov; idx = oi; }
  }
  int i1 = idx;

  float a2 = (lane == i1) ? -INFINITY : a;
  v = a2;
  idx = lane;
#pragma unroll
  for (int off = 32; off > 0; off >>= 1) {
    float ov = __shfl_xor(v, off, 64);
    int oi = __shfl_xor(idx, off, 64);
    if (ov > v || (ov == v && oi < idx)) { v = ov; idx = oi; }
  }
  int i2 = idx;

  if (lane == 0) {
    idx_out[(size_t)row * 2 + 0] = (float)i1;
    idx_out[(size_t)row * 2 + 1] = (float)i2;
  }
}

// ---------------------------------------------------------------------------
extern "C" void kernel_launch(void* const* d_in, const int* in_sizes, int n_in,
                              void* d_out, int out_size, void* d_ws,
                              size_t ws_size, hipStream_t stream) {
  const float* h = (const float*)d_in[0];   // [4,4096,4096]
  const float* wr = (const float*)d_in[1];  // [4096,64]
  float* out = (float*)d_out;
  float* logits = out;                          // ROWS*EE (raw, then adjusted)
  float* idx_out = out + (size_t)ROWS * EE;     // ROWS*2
  float* g_load = (float*)d_ws;                 // 64 floats
  unsigned char* wsp = (unsigned char*)d_ws + 512;  // 1 MiB pre-split w

  // no memsets: g_load zeroed in k_wsplit (stream-ordered); d_out fully
  // overwritten (logits by k_gemm stores, idx by k_top2).
  k_wsplit<<<DD / 32, 256, 0, stream>>>(wr, wsp, g_load);
  k_gemm<<<ROWS / BM, 256, 0, stream>>>(h, wsp, logits, g_load);
  k_top2<<<ROWS / 4, 256, 0, stream>>>(logits, g_load, idx_out);
}